// Round 1
// baseline (2303.730 us; speedup 1.0000x reference)
//
#include <hip/hip_runtime.h>

#define N_ROWS 131072
#define D 64
#define K 1024
#define KT 8

// ws layout (byte offsets): [0, 4096) e2 float[1024]; [4096, 8192) hist int[1024]; [8192] loss accum float

__global__ __launch_bounds__(256) void prep_kernel(const float* __restrict__ E,
                                                   float* __restrict__ e2,
                                                   int* __restrict__ hist,
                                                   float* __restrict__ loss_acc) {
    int k = blockIdx.x * blockDim.x + threadIdx.x;
    if (k < K) {
        float s = 0.f;
#pragma unroll
        for (int d = 0; d < D; ++d) {
            float v = E[d * K + k];
            s = fmaf(v, v, s);
        }
        e2[k] = s;
        hist[k] = 0;
        if (k == 0) *loss_acc = 0.f;
    }
}

__global__ __launch_bounds__(256) void vq_kernel(const float* __restrict__ X,
                                                 const float* __restrict__ E,
                                                 const float* __restrict__ e2,
                                                 int* __restrict__ hist,
                                                 float* __restrict__ loss_acc,
                                                 float* __restrict__ q_out) {
    int row = blockIdx.x * 256 + threadIdx.x;

    // Load this thread's row into registers (64 VGPRs).
    float x[D];
    const float4* xr = (const float4*)(X + (size_t)row * D);
#pragma unroll
    for (int i = 0; i < D / 4; ++i) {
        float4 v = xr[i];
        x[4 * i + 0] = v.x;
        x[4 * i + 1] = v.y;
        x[4 * i + 2] = v.z;
        x[4 * i + 3] = v.w;
    }

    float x2 = 0.f;
#pragma unroll
    for (int d = 0; d < D; ++d) x2 = fmaf(x[d], x[d], x2);

    float best = 3.4e38f, second = 3.4e38f;
    int besti = 0, secondi = 0;

    // E accesses below are wave-uniform (loop-var indices only) -> s_load path.
    for (int k0 = 0; k0 < K; k0 += KT) {
        float acc[KT];
#pragma unroll
        for (int j = 0; j < KT; ++j) acc[j] = 0.f;
#pragma unroll
        for (int d = 0; d < D; ++d) {
#pragma unroll
            for (int j = 0; j < KT; ++j)
                acc[j] = fmaf(x[d], E[d * K + k0 + j], acc[j]);
        }
#pragma unroll
        for (int j = 0; j < KT; ++j) {
            float dist = x2 - 2.f * acc[j] + e2[k0 + j];
            int ki = k0 + j;
            // strict < : earliest index wins ties (matches jnp.argmax(-dist) first-occurrence)
            if (dist < best) {
                second = best; secondi = besti;
                best = dist;   besti = ki;
            } else if (dist < second) {
                second = dist; secondi = ki;
            }
        }
    }

    // Near-tie refinement: decide by exact (fp64) squared distance.
    if (second - best < 1e-3f) {
        double d0 = 0.0, d1 = 0.0;
#pragma unroll
        for (int d = 0; d < D; ++d) {
            double t0 = (double)x[d] - (double)E[d * K + besti];
            double t1 = (double)x[d] - (double)E[d * K + secondi];
            d0 += t0 * t0;
            d1 += t1 * t1;
        }
        if (d1 < d0 || (d1 == d0 && secondi < besti)) besti = secondi;
    }

    atomicAdd(&hist[besti], 1);

    // Gather codebook row, compute loss contribution, straight-through output.
    float ls = 0.f;
#pragma unroll
    for (int d = 0; d < D; ++d) {
        float e = E[d * K + besti];
        float diff = e - x[d];
        ls = fmaf(diff, diff, ls);
        x[d] = x[d] + diff;  // mimics inpt + (q - inpt)
    }

    float4* qo = (float4*)(q_out + (size_t)row * D);
#pragma unroll
    for (int i = 0; i < D / 4; ++i) {
        float4 v;
        v.x = x[4 * i + 0];
        v.y = x[4 * i + 1];
        v.z = x[4 * i + 2];
        v.w = x[4 * i + 3];
        qo[i] = v;
    }

    // Block-level loss reduction: wave shuffle -> LDS -> one atomic per block.
    for (int off = 32; off > 0; off >>= 1) ls += __shfl_down(ls, off, 64);
    __shared__ float red[4];
    int lane = threadIdx.x & 63, wid = threadIdx.x >> 6;
    if (lane == 0) red[wid] = ls;
    __syncthreads();
    if (threadIdx.x == 0) atomicAdd(loss_acc, red[0] + red[1] + red[2] + red[3]);
}

__global__ __launch_bounds__(1024) void finalize_kernel(const int* __restrict__ hist,
                                                        const float* __restrict__ loss_acc,
                                                        float* __restrict__ out) {
    __shared__ float red[16];
    int tid = threadIdx.x;  // 1024 threads, one per bin
    float c = (float)hist[tid];
    float p = c * (1.0f / (float)N_ROWS);
    float term = p * logf(p + 1e-10f);
    for (int off = 32; off > 0; off >>= 1) term += __shfl_down(term, off, 64);
    int lane = tid & 63, wid = tid >> 6;
    if (lane == 0) red[wid] = term;
    __syncthreads();
    if (tid == 0) {
        float H = 0.f;
#pragma unroll
        for (int i = 0; i < 16; ++i) H += red[i];
        float m = *loss_acc / (float)(N_ROWS * D);
        out[N_ROWS * D + 0] = 2.0f * m;   // B_COMMITMENT * l_commitment + l_codebook
        out[N_ROWS * D + 1] = expf(-H);   // perplexity
    }
}

extern "C" void kernel_launch(void* const* d_in, const int* in_sizes, int n_in,
                              void* d_out, int out_size, void* d_ws, size_t ws_size,
                              hipStream_t stream) {
    const float* X = (const float*)d_in[0];   // [64,2048,64] fp32
    const float* E = (const float*)d_in[1];   // [64,1024]   fp32
    float* out = (float*)d_out;               // q (8388608) + loss + perplexity

    float* e2 = (float*)d_ws;
    int* hist = (int*)((char*)d_ws + 4096);
    float* lacc = (float*)((char*)d_ws + 8192);

    prep_kernel<<<4, 256, 0, stream>>>(E, e2, hist, lacc);
    vq_kernel<<<N_ROWS / 256, 256, 0, stream>>>(X, E, e2, hist, lacc, out);
    finalize_kernel<<<1, 1024, 0, stream>>>(hist, lacc, out);
}

// Round 2
// 249.833 us; speedup vs baseline: 9.2211x; 9.2211x over previous
//
#include <hip/hip_runtime.h>

#define NROWS 131072
#define D 64
#define K 1024

typedef __attribute__((ext_vector_type(8))) short short8;
typedef __attribute__((ext_vector_type(4))) float f32x4;

// ws layout (bytes):
//   [0, 4096)            e2h  float[1024]   = -0.5*||e_k||^2
//   [4096, 135168)       ehT  ushort[1024][64]  bf16 hi, [code][d]
//   [135168, 266240)     elT  ushort[1024][64]  bf16 lo
//   [266240, 528384)     eTf  float[1024][64]   fp32 codebook transposed
//   [528384, 1052672)    idx  int[131072]
//   [1052672, 1056768)   hist int[1024]
//   [1056768, ...)       lacc float

__device__ __forceinline__ unsigned short f2bf(float f) {
    unsigned u = __float_as_uint(f);
    u += 0x7fff + ((u >> 16) & 1);   // round-to-nearest-even
    return (unsigned short)(u >> 16);
}
__device__ __forceinline__ float bf2f(unsigned short s) {
    return __uint_as_float(((unsigned)s) << 16);
}

__global__ __launch_bounds__(256) void prep_kernel(const float* __restrict__ E,
                                                   unsigned short* __restrict__ ehT,
                                                   unsigned short* __restrict__ elT,
                                                   float* __restrict__ eTf,
                                                   float* __restrict__ e2h,
                                                   int* __restrict__ hist,
                                                   float* __restrict__ lacc) {
    int k = blockIdx.x * 256 + threadIdx.x;  // 1024 threads, one per code
    float s = 0.f;
#pragma unroll
    for (int d = 0; d < D; ++d) {
        float v = E[d * K + k];              // coalesced across threads
        s = fmaf(v, v, s);
        unsigned short h = f2bf(v);
        ehT[k * D + d] = h;
        elT[k * D + d] = f2bf(v - bf2f(h));
        eTf[k * D + d] = v;
    }
    e2h[k] = -0.5f * s;
    hist[k] = 0;
    if (k == 0) *lacc = 0.f;
}

__global__ __launch_bounds__(256) void score_kernel(const float* __restrict__ X,
                                                    const unsigned short* __restrict__ ehT,
                                                    const unsigned short* __restrict__ elT,
                                                    const float* __restrict__ e2h,
                                                    int* __restrict__ idx_out) {
    const int wave = threadIdx.x >> 6;
    const int lane = threadIdx.x & 63;
    const int quad = lane >> 4;
    const int lc = lane & 15;
    const int row_base = blockIdx.x * 128 + wave * 32;  // 2 strips of 16 rows per wave

    // A fragments: A[m=lane&15][k=quad*8+j], built from fp32 X, bf16-split.
    short8 axh[2][2], axl[2][2];  // [strip][kstep]
#pragma unroll
    for (int s = 0; s < 2; ++s) {
        const float* xr = X + (size_t)(row_base + s * 16 + lc) * D;
#pragma unroll
        for (int ks = 0; ks < 2; ++ks) {
            const float4* p = (const float4*)(xr + ks * 32 + quad * 8);
            float4 va = p[0], vb = p[1];
            float f[8] = {va.x, va.y, va.z, va.w, vb.x, vb.y, vb.z, vb.w};
            short8 h, l;
#pragma unroll
            for (int j = 0; j < 8; ++j) {
                unsigned short hh = f2bf(f[j]);
                h[j] = (short)hh;
                l[j] = (short)f2bf(f[j] - bf2f(hh));
            }
            axh[s][ks] = h;
            axl[s][ks] = l;
        }
    }

    float best[2][4];
    int bidx[2][4];
#pragma unroll
    for (int s = 0; s < 2; ++s)
#pragma unroll
        for (int r = 0; r < 4; ++r) { best[s][r] = -3.4e38f; bidx[s][r] = 0; }

    // B fragments: B[n=lane&15][k=quad*8+j] from transposed codebook [code][d].
    const unsigned short* ehp = ehT + (size_t)lc * D + quad * 8;
    const unsigned short* elp = elT + (size_t)lc * D + quad * 8;

    // software-pipelined prefetch of tile 0
    short8 beh0 = *(const short8*)(ehp);
    short8 beh1 = *(const short8*)(ehp + 32);
    short8 bel0 = *(const short8*)(elp);
    short8 bel1 = *(const short8*)(elp + 32);
    float e2c = e2h[lc];

    for (int tile = 0; tile < 64; ++tile) {
        const int code = tile * 16 + lc;
        short8 ch0 = beh0, ch1 = beh1, cl0 = bel0, cl1 = bel1;
        float ce2 = e2c;
        if (tile < 63) {
            const unsigned short* nh = ehp + (size_t)(tile + 1) * 16 * D;
            const unsigned short* nl = elp + (size_t)(tile + 1) * 16 * D;
            beh0 = *(const short8*)(nh);
            beh1 = *(const short8*)(nh + 32);
            bel0 = *(const short8*)(nl);
            bel1 = *(const short8*)(nl + 32);
            e2c = e2h[code + 16];
        }
#pragma unroll
        for (int s = 0; s < 2; ++s) {
            // acc = x.e - 0.5*||e||^2  (argmax of this == argmin of squared dist)
            f32x4 acc = {ce2, ce2, ce2, ce2};
            acc = __builtin_amdgcn_mfma_f32_16x16x32_bf16(axh[s][0], ch0, acc, 0, 0, 0);
            acc = __builtin_amdgcn_mfma_f32_16x16x32_bf16(axh[s][1], ch1, acc, 0, 0, 0);
            acc = __builtin_amdgcn_mfma_f32_16x16x32_bf16(axh[s][0], cl0, acc, 0, 0, 0);
            acc = __builtin_amdgcn_mfma_f32_16x16x32_bf16(axh[s][1], cl1, acc, 0, 0, 0);
            acc = __builtin_amdgcn_mfma_f32_16x16x32_bf16(axl[s][0], ch0, acc, 0, 0, 0);
            acc = __builtin_amdgcn_mfma_f32_16x16x32_bf16(axl[s][1], ch1, acc, 0, 0, 0);
            acc = __builtin_amdgcn_mfma_f32_16x16x32_bf16(axl[s][0], cl0, acc, 0, 0, 0);
            acc = __builtin_amdgcn_mfma_f32_16x16x32_bf16(axl[s][1], cl1, acc, 0, 0, 0);
#pragma unroll
            for (int r = 0; r < 4; ++r) {
                // strict > : ascending code order => lowest index wins ties
                if (acc[r] > best[s][r]) { best[s][r] = acc[r]; bidx[s][r] = code; }
            }
        }
    }

    // Merge across the 16 lanes of each quad-group (they share rows, partition codes).
#pragma unroll
    for (int off = 1; off <= 8; off <<= 1) {
#pragma unroll
        for (int s = 0; s < 2; ++s)
#pragma unroll
            for (int r = 0; r < 4; ++r) {
                float ob = __shfl_xor(best[s][r], off, 64);
                int oi = __shfl_xor(bidx[s][r], off, 64);
                if (ob > best[s][r] || (ob == best[s][r] && oi < bidx[s][r])) {
                    best[s][r] = ob;
                    bidx[s][r] = oi;
                }
            }
    }

    if (lc == 0) {
        // C/D row = quad*4 + r
#pragma unroll
        for (int s = 0; s < 2; ++s)
#pragma unroll
            for (int r = 0; r < 4; ++r)
                idx_out[row_base + s * 16 + quad * 4 + r] = bidx[s][r];
    }
}

__global__ __launch_bounds__(256) void gather_kernel(const float* __restrict__ X,
                                                     const float* __restrict__ eTf,
                                                     const int* __restrict__ idx,
                                                     int* __restrict__ hist,
                                                     float* __restrict__ lacc,
                                                     float* __restrict__ q) {
    int row = blockIdx.x * 256 + threadIdx.x;
    int k = idx[row];
    const float4* xr = (const float4*)(X + (size_t)row * D);
    const float4* er = (const float4*)(eTf + (size_t)k * D);
    float4* qo = (float4*)(q + (size_t)row * D);
    float ls = 0.f;
#pragma unroll
    for (int i = 0; i < 16; ++i) {
        float4 xv = xr[i], ev = er[i];
        float4 o;
        float dx = ev.x - xv.x; ls = fmaf(dx, dx, ls); o.x = xv.x + dx;
        float dy = ev.y - xv.y; ls = fmaf(dy, dy, ls); o.y = xv.y + dy;
        float dz = ev.z - xv.z; ls = fmaf(dz, dz, ls); o.z = xv.z + dz;
        float dw = ev.w - xv.w; ls = fmaf(dw, dw, ls); o.w = xv.w + dw;
        qo[i] = o;
    }
    atomicAdd(&hist[k], 1);
    for (int off = 32; off > 0; off >>= 1) ls += __shfl_down(ls, off, 64);
    __shared__ float red[4];
    int lane = threadIdx.x & 63, wid = threadIdx.x >> 6;
    if (lane == 0) red[wid] = ls;
    __syncthreads();
    if (threadIdx.x == 0) atomicAdd(lacc, red[0] + red[1] + red[2] + red[3]);
}

__global__ __launch_bounds__(1024) void finalize_kernel(const int* __restrict__ hist,
                                                        const float* __restrict__ lacc,
                                                        float* __restrict__ out) {
    __shared__ float red[16];
    int tid = threadIdx.x;
    float p = (float)hist[tid] * (1.0f / (float)NROWS);
    float term = p * logf(p + 1e-10f);
    for (int off = 32; off > 0; off >>= 1) term += __shfl_down(term, off, 64);
    int lane = tid & 63, wid = tid >> 6;
    if (lane == 0) red[wid] = term;
    __syncthreads();
    if (tid == 0) {
        float H = 0.f;
#pragma unroll
        for (int i = 0; i < 16; ++i) H += red[i];
        float m = *lacc / (float)(NROWS * D);
        out[(size_t)NROWS * D + 0] = 2.0f * m;   // commitment + codebook loss
        out[(size_t)NROWS * D + 1] = expf(-H);   // perplexity
    }
}

extern "C" void kernel_launch(void* const* d_in, const int* in_sizes, int n_in,
                              void* d_out, int out_size, void* d_ws, size_t ws_size,
                              hipStream_t stream) {
    const float* X = (const float*)d_in[0];   // [64,2048,64] fp32
    const float* E = (const float*)d_in[1];   // [64,1024]   fp32
    float* out = (float*)d_out;

    char* w = (char*)d_ws;
    float* e2h          = (float*)(w + 0);
    unsigned short* ehT = (unsigned short*)(w + 4096);
    unsigned short* elT = (unsigned short*)(w + 135168);
    float* eTf          = (float*)(w + 266240);
    int* idx            = (int*)(w + 528384);
    int* hist           = (int*)(w + 1052672);
    float* lacc         = (float*)(w + 1056768);

    prep_kernel<<<4, 256, 0, stream>>>(E, ehT, elT, eTf, e2h, hist, lacc);
    score_kernel<<<NROWS / 128, 256, 0, stream>>>(X, ehT, elT, e2h, idx);
    gather_kernel<<<NROWS / 256, 256, 0, stream>>>(X, eTf, idx, hist, lacc, out);
    finalize_kernel<<<1, 1024, 0, stream>>>(hist, lacc, out);
}

// Round 3
// 192.385 us; speedup vs baseline: 11.9746x; 1.2986x over previous
//
#include <hip/hip_runtime.h>

#define NROWS 131072
#define D 64
#define K 1024

typedef __attribute__((ext_vector_type(8))) short short8;
typedef __attribute__((ext_vector_type(4))) float f32x4;

// ws layout (bytes):
//   [0, 4096)          e2h  float[1024]        = -0.5*||e_k||^2
//   [4096, 135168)     ehT  ushort[1024][64]   bf16 hi, [code][d]
//   [135168, 266240)   elT  ushort[1024][64]   bf16 lo
//   [266240, 528384)   eTf  float[1024][64]    fp32 codebook transposed
//   [528384, 536576)   wavesum float[2048]     per-wave loss partials
//   [536576, 540672)   hist int[1024]

__device__ __forceinline__ unsigned short f2bf(float f) {
    unsigned u = __float_as_uint(f);
    u += 0x7fff + ((u >> 16) & 1);   // round-to-nearest-even
    return (unsigned short)(u >> 16);
}
__device__ __forceinline__ float bf2f(unsigned short s) {
    return __uint_as_float(((unsigned)s) << 16);
}

__global__ __launch_bounds__(256) void prep_kernel(const float* __restrict__ E,
                                                   unsigned short* __restrict__ ehT,
                                                   unsigned short* __restrict__ elT,
                                                   float* __restrict__ eTf,
                                                   float* __restrict__ e2h,
                                                   int* __restrict__ hist) {
    int k = blockIdx.x * 256 + threadIdx.x;  // 1024 threads, one per code
    float s = 0.f;
#pragma unroll
    for (int db = 0; db < 8; ++db) {
        float f[8];
        short8 h8, l8;
#pragma unroll
        for (int j = 0; j < 8; ++j) {
            float v = E[(db * 8 + j) * K + k];   // coalesced across lanes
            f[j] = v;
            s = fmaf(v, v, s);
            unsigned short h = f2bf(v);
            h8[j] = (short)h;
            l8[j] = (short)f2bf(v - bf2f(h));
        }
        *(short8*)(ehT + (size_t)k * D + db * 8) = h8;
        *(short8*)(elT + (size_t)k * D + db * 8) = l8;
        float4 a = {f[0], f[1], f[2], f[3]}, b = {f[4], f[5], f[6], f[7]};
        ((float4*)(eTf + (size_t)k * D + db * 8))[0] = a;
        ((float4*)(eTf + (size_t)k * D + db * 8))[1] = b;
    }
    e2h[k] = -0.5f * s;
    hist[k] = 0;
}

__global__ __launch_bounds__(256) void score_fused_kernel(const float* __restrict__ X,
                                                          const unsigned short* __restrict__ ehT,
                                                          const unsigned short* __restrict__ elT,
                                                          const float* __restrict__ e2h,
                                                          const float* __restrict__ eTf,
                                                          int* __restrict__ hist,
                                                          float* __restrict__ wavesum,
                                                          float* __restrict__ q) {
    const int wave = threadIdx.x >> 6;
    const int lane = threadIdx.x & 63;
    const int quad = lane >> 4;
    const int lc = lane & 15;
    const int row_base = blockIdx.x * 256 + wave * 64;  // 4 strips of 16 rows per wave

    // A fragments: A[m=lane&15][k=quad*8+j], bf16-split from fp32 X.
    short8 axh[4][2], axl[4][2];  // [strip][kstep]
#pragma unroll
    for (int s = 0; s < 4; ++s) {
        const float* xr = X + (size_t)(row_base + s * 16 + lc) * D;
#pragma unroll
        for (int ks = 0; ks < 2; ++ks) {
            const float4* p = (const float4*)(xr + ks * 32 + quad * 8);
            float4 va = p[0], vb = p[1];
            float f[8] = {va.x, va.y, va.z, va.w, vb.x, vb.y, vb.z, vb.w};
            short8 h, l;
#pragma unroll
            for (int j = 0; j < 8; ++j) {
                unsigned short hh = f2bf(f[j]);
                h[j] = (short)hh;
                l[j] = (short)f2bf(f[j] - bf2f(hh));
            }
            axh[s][ks] = h;
            axl[s][ks] = l;
        }
    }

    float best[4][4];
    int bidx[4][4];
#pragma unroll
    for (int s = 0; s < 4; ++s)
#pragma unroll
        for (int r = 0; r < 4; ++r) { best[s][r] = -3.4e38f; bidx[s][r] = 0; }

    // B fragments: B[n=lane&15][k=quad*8+j] from [code][d] layout.
    const unsigned short* ehp = ehT + (size_t)lc * D + quad * 8;
    const unsigned short* elp = elT + (size_t)lc * D + quad * 8;

    short8 beh0 = *(const short8*)(ehp);
    short8 beh1 = *(const short8*)(ehp + 32);
    short8 bel0 = *(const short8*)(elp);
    short8 bel1 = *(const short8*)(elp + 32);
    float e2c = e2h[lc];

    for (int tile = 0; tile < 64; ++tile) {
        const int code = tile * 16 + lc;
        short8 ch0 = beh0, ch1 = beh1, cl0 = bel0, cl1 = bel1;
        float ce2 = e2c;
        if (tile < 63) {
            const unsigned short* nh = ehp + (size_t)(tile + 1) * 16 * D;
            const unsigned short* nl = elp + (size_t)(tile + 1) * 16 * D;
            beh0 = *(const short8*)(nh);
            beh1 = *(const short8*)(nh + 32);
            bel0 = *(const short8*)(nl);
            bel1 = *(const short8*)(nl + 32);
            e2c = e2h[code + 16];
        }
#pragma unroll
        for (int s = 0; s < 4; ++s) {
            // acc = x.e - 0.5||e||^2 ; 3-product bf16 split (hi*hi + hi*lo + lo*hi)
            f32x4 acc = {ce2, ce2, ce2, ce2};
            acc = __builtin_amdgcn_mfma_f32_16x16x32_bf16(axh[s][0], ch0, acc, 0, 0, 0);
            acc = __builtin_amdgcn_mfma_f32_16x16x32_bf16(axh[s][1], ch1, acc, 0, 0, 0);
            acc = __builtin_amdgcn_mfma_f32_16x16x32_bf16(axh[s][0], cl0, acc, 0, 0, 0);
            acc = __builtin_amdgcn_mfma_f32_16x16x32_bf16(axh[s][1], cl1, acc, 0, 0, 0);
            acc = __builtin_amdgcn_mfma_f32_16x16x32_bf16(axl[s][0], ch0, acc, 0, 0, 0);
            acc = __builtin_amdgcn_mfma_f32_16x16x32_bf16(axl[s][1], ch1, acc, 0, 0, 0);
#pragma unroll
            for (int r = 0; r < 4; ++r) {
                if (acc[r] > best[s][r]) { best[s][r] = acc[r]; bidx[s][r] = code; }
            }
        }
    }

    // Merge across the 16 lanes sharing rows (lc dimension partitions codes).
#pragma unroll
    for (int off = 1; off <= 8; off <<= 1) {
#pragma unroll
        for (int s = 0; s < 4; ++s)
#pragma unroll
            for (int r = 0; r < 4; ++r) {
                float ob = __shfl_xor(best[s][r], off, 64);
                int oi = __shfl_xor(bidx[s][r], off, 64);
                if (ob > best[s][r] || (ob == best[s][r] && oi < bidx[s][r])) {
                    best[s][r] = ob;
                    bidx[s][r] = oi;
                }
            }
    }

    // Exchange indices so lane i owns row (row_base + i).
    __shared__ int idxs[4][64];
    if (lc == 0) {
#pragma unroll
        for (int s = 0; s < 4; ++s)
#pragma unroll
            for (int r = 0; r < 4; ++r)
                idxs[wave][s * 16 + quad * 4 + r] = bidx[s][r];
    }
    __syncthreads();

    const int k = idxs[wave][lane];
    const int row = row_base + lane;
    atomicAdd(&hist[k], 1);

    const float4* xr = (const float4*)(X + (size_t)row * D);
    const float4* er = (const float4*)(eTf + (size_t)k * D);
    float4* qo = (float4*)(q + (size_t)row * D);
    float ls = 0.f;
#pragma unroll
    for (int i = 0; i < 16; ++i) {
        float4 xv = xr[i], ev = er[i];
        float4 o;
        float dx = ev.x - xv.x; ls = fmaf(dx, dx, ls); o.x = xv.x + dx;
        float dy = ev.y - xv.y; ls = fmaf(dy, dy, ls); o.y = xv.y + dy;
        float dz = ev.z - xv.z; ls = fmaf(dz, dz, ls); o.z = xv.z + dz;
        float dw = ev.w - xv.w; ls = fmaf(dw, dw, ls); o.w = xv.w + dw;
        qo[i] = o;
    }
    for (int off = 32; off > 0; off >>= 1) ls += __shfl_down(ls, off, 64);
    if (lane == 0) wavesum[blockIdx.x * 4 + wave] = ls;
}

__global__ __launch_bounds__(1024) void finalize_kernel(const int* __restrict__ hist,
                                                        const float* __restrict__ wavesum,
                                                        float* __restrict__ out) {
    __shared__ float redH[16], redL[16];
    int tid = threadIdx.x;
    float p = (float)hist[tid] * (1.0f / (float)NROWS);
    float term = p * logf(p + 1e-10f);
    float ls = wavesum[tid] + wavesum[tid + 1024];
    for (int off = 32; off > 0; off >>= 1) {
        term += __shfl_down(term, off, 64);
        ls += __shfl_down(ls, off, 64);
    }
    int lane = tid & 63, wid = tid >> 6;
    if (lane == 0) { redH[wid] = term; redL[wid] = ls; }
    __syncthreads();
    if (tid == 0) {
        float H = 0.f, L = 0.f;
#pragma unroll
        for (int i = 0; i < 16; ++i) { H += redH[i]; L += redL[i]; }
        out[(size_t)NROWS * D + 0] = 2.0f * (L / (float)(NROWS * D));
        out[(size_t)NROWS * D + 1] = expf(-H);
    }
}

extern "C" void kernel_launch(void* const* d_in, const int* in_sizes, int n_in,
                              void* d_out, int out_size, void* d_ws, size_t ws_size,
                              hipStream_t stream) {
    const float* X = (const float*)d_in[0];   // [64,2048,64] fp32
    const float* E = (const float*)d_in[1];   // [64,1024]   fp32
    float* out = (float*)d_out;

    char* w = (char*)d_ws;
    float* e2h          = (float*)(w + 0);
    unsigned short* ehT = (unsigned short*)(w + 4096);
    unsigned short* elT = (unsigned short*)(w + 135168);
    float* eTf          = (float*)(w + 266240);
    float* wavesum      = (float*)(w + 528384);
    int* hist           = (int*)(w + 536576);

    prep_kernel<<<4, 256, 0, stream>>>(E, ehT, elT, eTf, e2h, hist);
    score_fused_kernel<<<NROWS / 256, 256, 0, stream>>>(X, ehT, elT, e2h, eTf, hist, wavesum, out);
    finalize_kernel<<<1, 1024, 0, stream>>>(hist, wavesum, out);
}

// Round 4
// 144.455 us; speedup vs baseline: 15.9478x; 1.3318x over previous
//
#include <hip/hip_runtime.h>

#define NROWS 131072
#define D 64
#define K 1024

typedef __attribute__((ext_vector_type(8))) short short8;
typedef __attribute__((ext_vector_type(4))) float f32x4;

// ws layout (bytes):
//   [0, 131072)        ehT  ushort[1024][64]  bf16 hi, [code][d]
//   [131072, 393216)   eTf  float[1024][64]   fp32 codebook transposed
//   [393216, 409600)   e2p  float[4][1024]    partial ||e||^2 sums
//   [409600, 413696)   hist int[1024]
//   [413696, 421888)   wavesum float[2048]

__device__ __forceinline__ unsigned short f2bf(float f) {
    unsigned u = __float_as_uint(f);
    u += 0x7fff + ((u >> 16) & 1);   // round-to-nearest-even
    return (unsigned short)(u >> 16);
}

__global__ __launch_bounds__(256) void prep_kernel(const float* __restrict__ E,
                                                   unsigned short* __restrict__ ehT,
                                                   float* __restrict__ eTf,
                                                   float* __restrict__ e2p,
                                                   int* __restrict__ hist) {
    // 16 blocks x 256: k = (blk&3)*256 + tid, dq = blk>>2 ; thread does d = dq*16..dq*16+15
    const int k = (blockIdx.x & 3) * 256 + threadIdx.x;
    const int dq = blockIdx.x >> 2;
    float f[16];
    float s = 0.f;
#pragma unroll
    for (int j = 0; j < 16; ++j) {
        float v = E[(dq * 16 + j) * K + k];   // coalesced across lanes
        f[j] = v;
        s = fmaf(v, v, s);
    }
    short8 h0, h1;
#pragma unroll
    for (int j = 0; j < 8; ++j) {
        h0[j] = (short)f2bf(f[j]);
        h1[j] = (short)f2bf(f[8 + j]);
    }
    *(short8*)(ehT + (size_t)k * D + dq * 16) = h0;
    *(short8*)(ehT + (size_t)k * D + dq * 16 + 8) = h1;
#pragma unroll
    for (int c = 0; c < 4; ++c) {
        float4 v = {f[c * 4], f[c * 4 + 1], f[c * 4 + 2], f[c * 4 + 3]};
        *(float4*)(eTf + (size_t)k * D + dq * 16 + c * 4) = v;
    }
    e2p[dq * K + k] = s;
    if (dq == 0) hist[k] = 0;
}

__global__ __launch_bounds__(512) void score_kernel(const float* __restrict__ X,
                                                    const unsigned short* __restrict__ ehT,
                                                    const float* __restrict__ e2p,
                                                    const float* __restrict__ eTf,
                                                    int* __restrict__ hist,
                                                    float* __restrict__ wavesum,
                                                    float* __restrict__ q) {
    __shared__ unsigned short ehs[256 * 64];  // 32 KB, XOR-swizzled [code][unit^(code&7)]
    __shared__ float e2s[256];
    __shared__ int idxs[512];

    const int wave = threadIdx.x >> 6;
    const int lane = threadIdx.x & 63;
    const int quad = lane >> 4;
    const int lc = lane & 15;
    const size_t row0 = (size_t)blockIdx.x * 512 + wave * 64;

    // ---- prologue: A fragments (bf16-hi), A[m=lc][k=quad*8+j] ----
    short8 ax[4][2];
#pragma unroll
    for (int s = 0; s < 4; ++s) {
        const float* xr = X + (row0 + s * 16 + lc) * D;
#pragma unroll
        for (int ks = 0; ks < 2; ++ks) {
            float4 a = *(const float4*)(xr + ks * 32 + quad * 8);
            float4 b = *(const float4*)(xr + ks * 32 + quad * 8 + 4);
            float f[8] = {a.x, a.y, a.z, a.w, b.x, b.y, b.z, b.w};
            short8 h;
#pragma unroll
            for (int j = 0; j < 8; ++j) h[j] = (short)f2bf(f[j]);
            ax[s][ks] = h;
        }
    }

    float best[4][4];
    int bidx[4][4];
#pragma unroll
    for (int s = 0; s < 4; ++s)
#pragma unroll
        for (int r = 0; r < 4; ++r) { best[s][r] = -3.4e38f; bidx[s][r] = 0; }

    // per-lane constant swizzled LDS byte offsets for B fragments
    const int boff0 = lc * 128 + ((quad ^ (lc & 7)) * 16);
    const int boff1 = lc * 128 + (((quad + 4) ^ (lc & 7)) * 16);

    for (int p = 0; p < 4; ++p) {
        if (p) __syncthreads();  // previous pass fully consumed before overwrite
        // ---- stage 256 codes (32 KB): 2048 x 16B slots over 512 threads ----
#pragma unroll
        for (int r = 0; r < 4; ++r) {
            int slot = r * 512 + threadIdx.x;
            int c = slot >> 3;        // code within pass
            int o = slot & 7;         // 16B unit within row
            short8 v = *(const short8*)(ehT + ((size_t)(p * 256 + c) * D + o * 8));
            *(short8*)((char*)ehs + c * 128 + ((o ^ (c & 7)) * 16)) = v;
        }
        if (threadIdx.x < 256) {
            int gk = p * 256 + threadIdx.x;
            e2s[threadIdx.x] = -0.5f * (e2p[gk] + e2p[K + gk] + e2p[2 * K + gk] + e2p[3 * K + gk]);
        }
        __syncthreads();

        // ---- 16 tiles of 16 codes ----
#pragma unroll 4
        for (int t = 0; t < 16; ++t) {
            const int cc = t * 16 + lc;           // code within pass
            const int code = p * 256 + cc;
            short8 eb0 = *(const short8*)((char*)ehs + t * 2048 + boff0);
            short8 eb1 = *(const short8*)((char*)ehs + t * 2048 + boff1);
            float ce2 = e2s[cc];
#pragma unroll
            for (int s = 0; s < 4; ++s) {
                f32x4 acc = {ce2, ce2, ce2, ce2};
                acc = __builtin_amdgcn_mfma_f32_16x16x32_bf16(ax[s][0], eb0, acc, 0, 0, 0);
                acc = __builtin_amdgcn_mfma_f32_16x16x32_bf16(ax[s][1], eb1, acc, 0, 0, 0);
#pragma unroll
                for (int r = 0; r < 4; ++r) {
                    if (acc[r] > best[s][r]) { best[s][r] = acc[r]; bidx[s][r] = code; }
                }
            }
        }
    }

    // ---- merge across the 16 lanes sharing rows ----
#pragma unroll
    for (int off = 1; off <= 8; off <<= 1) {
#pragma unroll
        for (int s = 0; s < 4; ++s)
#pragma unroll
            for (int r = 0; r < 4; ++r) {
                float ob = __shfl_xor(best[s][r], off, 64);
                int oi = __shfl_xor(bidx[s][r], off, 64);
                if (ob > best[s][r] || (ob == best[s][r] && oi < bidx[s][r])) {
                    best[s][r] = ob;
                    bidx[s][r] = oi;
                }
            }
    }

    // ---- wave-local index exchange (no barrier: same-wave LDS RAW is ordered) ----
    if (lc == 0) {
#pragma unroll
        for (int s = 0; s < 4; ++s)
#pragma unroll
            for (int r = 0; r < 4; ++r)
                idxs[wave * 64 + s * 16 + quad * 4 + r] = bidx[s][r];
    }
    int myk = idxs[wave * 64 + lane];
    atomicAdd(&hist[myk], 1);

    // ---- coalesced epilogue: 16 iterations x 4 rows (one per quad) ----
    float ls = 0.f;
#pragma unroll 4
    for (int it = 0; it < 16; ++it) {
        int rl = it * 4 + quad;
        int k = idxs[wave * 64 + rl];            // broadcast within quad-group
        size_t row = row0 + rl;
        float4 xv = *(const float4*)(X + row * D + lc * 4);
        float4 ev = *(const float4*)(eTf + (size_t)k * D + lc * 4);
        float4 o;
        float dx = ev.x - xv.x; ls = fmaf(dx, dx, ls); o.x = xv.x + dx;
        float dy = ev.y - xv.y; ls = fmaf(dy, dy, ls); o.y = xv.y + dy;
        float dz = ev.z - xv.z; ls = fmaf(dz, dz, ls); o.z = xv.z + dz;
        float dw = ev.w - xv.w; ls = fmaf(dw, dw, ls); o.w = xv.w + dw;
        *(float4*)(q + row * D + lc * 4) = o;
    }
    for (int off = 32; off > 0; off >>= 1) ls += __shfl_down(ls, off, 64);
    if (lane == 0) wavesum[blockIdx.x * 8 + wave] = ls;
}

__global__ __launch_bounds__(1024) void finalize_kernel(const int* __restrict__ hist,
                                                        const float* __restrict__ wavesum,
                                                        float* __restrict__ out) {
    __shared__ float redH[16], redL[16];
    int tid = threadIdx.x;
    float p = (float)hist[tid] * (1.0f / (float)NROWS);
    float term = p * logf(p + 1e-10f);
    float ls = wavesum[tid] + wavesum[tid + 1024];
    for (int off = 32; off > 0; off >>= 1) {
        term += __shfl_down(term, off, 64);
        ls += __shfl_down(ls, off, 64);
    }
    int lane = tid & 63, wid = tid >> 6;
    if (lane == 0) { redH[wid] = term; redL[wid] = ls; }
    __syncthreads();
    if (tid == 0) {
        float H = 0.f, L = 0.f;
#pragma unroll
        for (int i = 0; i < 16; ++i) { H += redH[i]; L += redL[i]; }
        out[(size_t)NROWS * D + 0] = 2.0f * (L / (float)(NROWS * D));
        out[(size_t)NROWS * D + 1] = expf(-H);
    }
}

extern "C" void kernel_launch(void* const* d_in, const int* in_sizes, int n_in,
                              void* d_out, int out_size, void* d_ws, size_t ws_size,
                              hipStream_t stream) {
    const float* X = (const float*)d_in[0];   // [64,2048,64] fp32
    const float* E = (const float*)d_in[1];   // [64,1024]   fp32
    float* out = (float*)d_out;

    char* w = (char*)d_ws;
    unsigned short* ehT = (unsigned short*)(w + 0);
    float* eTf          = (float*)(w + 131072);
    float* e2p          = (float*)(w + 393216);
    int* hist           = (int*)(w + 409600);
    float* wavesum      = (float*)(w + 413696);

    prep_kernel<<<16, 256, 0, stream>>>(E, ehT, eTf, e2p, hist);
    score_kernel<<<NROWS / 512, 512, 0, stream>>>(X, ehT, e2p, eTf, hist, wavesum, out);
    finalize_kernel<<<1, 1024, 0, stream>>>(hist, wavesum, out);
}

// Round 5
// 134.372 us; speedup vs baseline: 17.1444x; 1.0750x over previous
//
#include <hip/hip_runtime.h>

#define NROWS 131072
#define D 64
#define K 1024

typedef __attribute__((ext_vector_type(8))) short short8;
typedef __attribute__((ext_vector_type(4))) float f32x4;

// ws layout (bytes):
//   [0, 131072)        ehT  ushort[1024][64]  bf16 hi, [code][d]
//   [131072, 393216)   eTf  float[1024][64]   fp32 codebook transposed
//   [393216, 409600)   e2p  float[4][1024]    partial ||e||^2 sums
//   [409600, 413696)   hist int[1024]
//   [413696, 430080)   wavesum float[4096]

__device__ __forceinline__ unsigned short f2bf(float f) {
    unsigned u = __float_as_uint(f);
    u += 0x7fff + ((u >> 16) & 1);   // round-to-nearest-even
    return (unsigned short)(u >> 16);
}

__global__ __launch_bounds__(256) void prep_kernel(const float* __restrict__ E,
                                                   unsigned short* __restrict__ ehT,
                                                   float* __restrict__ eTf,
                                                   float* __restrict__ e2p,
                                                   int* __restrict__ hist) {
    // 16 blocks x 256: k = (blk&3)*256 + tid, dq = blk>>2 ; thread does d = dq*16..dq*16+15
    const int k = (blockIdx.x & 3) * 256 + threadIdx.x;
    const int dq = blockIdx.x >> 2;
    float f[16];
    float s = 0.f;
#pragma unroll
    for (int j = 0; j < 16; ++j) {
        float v = E[(dq * 16 + j) * K + k];   // coalesced across lanes
        f[j] = v;
        s = fmaf(v, v, s);
    }
    short8 h0, h1;
#pragma unroll
    for (int j = 0; j < 8; ++j) {
        h0[j] = (short)f2bf(f[j]);
        h1[j] = (short)f2bf(f[8 + j]);
    }
    *(short8*)(ehT + (size_t)k * D + dq * 16) = h0;
    *(short8*)(ehT + (size_t)k * D + dq * 16 + 8) = h1;
#pragma unroll
    for (int c = 0; c < 4; ++c) {
        float4 v = {f[c * 4], f[c * 4 + 1], f[c * 4 + 2], f[c * 4 + 3]};
        *(float4*)(eTf + (size_t)k * D + dq * 16 + c * 4) = v;
    }
    e2p[dq * K + k] = s;
    if (dq == 0) hist[k] = 0;
}

// 256 threads = 4 waves; wave handles 32 rows (2 strips of 16); block = 128 rows.
// grid = 1024 blocks -> 4 blocks/CU (LDS 4 x ~34 KB = 136 KB), 16 waves/CU.
__global__ __launch_bounds__(256, 4) void score_kernel(const float* __restrict__ X,
                                                       const unsigned short* __restrict__ ehT,
                                                       const float* __restrict__ e2p,
                                                       const float* __restrict__ eTf,
                                                       int* __restrict__ hist,
                                                       float* __restrict__ wavesum,
                                                       float* __restrict__ q) {
    __shared__ unsigned short ehs[256 * 64];  // 32 KB, XOR-swizzled [code][unit^(code&7)]
    __shared__ float e2s[256];
    __shared__ int idxs[4][32];

    const int wave = threadIdx.x >> 6;
    const int lane = threadIdx.x & 63;
    const int quad = lane >> 4;
    const int lc = lane & 15;
    const size_t row0 = (size_t)blockIdx.x * 128 + wave * 32;

    // ---- prologue: A fragments (bf16-hi), A[m=lc][k=quad*8+j] ----
    short8 ax[2][2];
#pragma unroll
    for (int s = 0; s < 2; ++s) {
        const float* xr = X + (row0 + s * 16 + lc) * D;
#pragma unroll
        for (int ks = 0; ks < 2; ++ks) {
            float4 a = *(const float4*)(xr + ks * 32 + quad * 8);
            float4 b = *(const float4*)(xr + ks * 32 + quad * 8 + 4);
            float f[8] = {a.x, a.y, a.z, a.w, b.x, b.y, b.z, b.w};
            short8 h;
#pragma unroll
            for (int j = 0; j < 8; ++j) h[j] = (short)f2bf(f[j]);
            ax[s][ks] = h;
        }
    }

    float best[2][4];
    int bidx[2][4];
#pragma unroll
    for (int s = 0; s < 2; ++s)
#pragma unroll
        for (int r = 0; r < 4; ++r) { best[s][r] = -3.4e38f; bidx[s][r] = 0; }

    // per-lane constant swizzled LDS byte offsets for B fragments
    const int boff0 = lc * 128 + ((quad ^ (lc & 7)) * 16);
    const int boff1 = lc * 128 + (((quad + 4) ^ (lc & 7)) * 16);

    for (int p = 0; p < 4; ++p) {
        if (p) __syncthreads();  // previous pass fully consumed before overwrite
        // ---- stage 256 codes (32 KB): 2048 x 16B slots over 256 threads ----
#pragma unroll
        for (int r = 0; r < 8; ++r) {
            int slot = r * 256 + threadIdx.x;
            int c = slot >> 3;        // code within pass
            int o = slot & 7;         // 16B unit within row
            short8 v = *(const short8*)(ehT + ((size_t)(p * 256 + c) * D + o * 8));
            *(short8*)((char*)ehs + c * 128 + ((o ^ (c & 7)) * 16)) = v;
        }
        if (threadIdx.x < 256) {
            int gk = p * 256 + threadIdx.x;
            e2s[threadIdx.x] = -0.5f * (e2p[gk] + e2p[K + gk] + e2p[2 * K + gk] + e2p[3 * K + gk]);
        }
        __syncthreads();

        // ---- 16 tiles of 16 codes ----
#pragma unroll 4
        for (int t = 0; t < 16; ++t) {
            const int cc = t * 16 + lc;           // code within pass
            const int code = p * 256 + cc;
            short8 eb0 = *(const short8*)((char*)ehs + t * 2048 + boff0);
            short8 eb1 = *(const short8*)((char*)ehs + t * 2048 + boff1);
            float ce2 = e2s[cc];
#pragma unroll
            for (int s = 0; s < 2; ++s) {
                f32x4 acc = {ce2, ce2, ce2, ce2};
                acc = __builtin_amdgcn_mfma_f32_16x16x32_bf16(ax[s][0], eb0, acc, 0, 0, 0);
                acc = __builtin_amdgcn_mfma_f32_16x16x32_bf16(ax[s][1], eb1, acc, 0, 0, 0);
#pragma unroll
                for (int r = 0; r < 4; ++r) {
                    if (acc[r] > best[s][r]) { best[s][r] = acc[r]; bidx[s][r] = code; }
                }
            }
        }
    }

    // ---- merge across the 16 lanes sharing rows ----
#pragma unroll
    for (int off = 1; off <= 8; off <<= 1) {
#pragma unroll
        for (int s = 0; s < 2; ++s)
#pragma unroll
            for (int r = 0; r < 4; ++r) {
                float ob = __shfl_xor(best[s][r], off, 64);
                int oi = __shfl_xor(bidx[s][r], off, 64);
                if (ob > best[s][r] || (ob == best[s][r] && oi < bidx[s][r])) {
                    best[s][r] = ob;
                    bidx[s][r] = oi;
                }
            }
    }

    // ---- wave-local index exchange (same-wave LDS RAW is ordered) ----
    if (lc == 0) {
#pragma unroll
        for (int s = 0; s < 2; ++s)
#pragma unroll
            for (int r = 0; r < 4; ++r)
                idxs[wave][s * 16 + quad * 4 + r] = bidx[s][r];
    }
    if (lane < 32) atomicAdd(&hist[idxs[wave][lane]], 1);

    // ---- coalesced epilogue: 8 iterations x 4 rows (one per quad) ----
    float ls = 0.f;
#pragma unroll 4
    for (int it = 0; it < 8; ++it) {
        int rl = it * 4 + quad;
        int k = idxs[wave][rl];                  // broadcast within quad-group
        size_t row = row0 + rl;
        float4 xv = *(const float4*)(X + row * D + lc * 4);
        float4 ev = *(const float4*)(eTf + (size_t)k * D + lc * 4);
        float4 o;
        float dx = ev.x - xv.x; ls = fmaf(dx, dx, ls); o.x = xv.x + dx;
        float dy = ev.y - xv.y; ls = fmaf(dy, dy, ls); o.y = xv.y + dy;
        float dz = ev.z - xv.z; ls = fmaf(dz, dz, ls); o.z = xv.z + dz;
        float dw = ev.w - xv.w; ls = fmaf(dw, dw, ls); o.w = xv.w + dw;
        *(float4*)(q + row * D + lc * 4) = o;
    }
    for (int off = 32; off > 0; off >>= 1) ls += __shfl_down(ls, off, 64);
    if (lane == 0) wavesum[blockIdx.x * 4 + wave] = ls;
}

__global__ __launch_bounds__(1024) void finalize_kernel(const int* __restrict__ hist,
                                                        const float* __restrict__ wavesum,
                                                        float* __restrict__ out) {
    __shared__ float redH[16], redL[16];
    int tid = threadIdx.x;
    float p = (float)hist[tid] * (1.0f / (float)NROWS);
    float term = p * logf(p + 1e-10f);
    float ls = wavesum[tid] + wavesum[tid + 1024] + wavesum[tid + 2048] + wavesum[tid + 3072];
    for (int off = 32; off > 0; off >>= 1) {
        term += __shfl_down(term, off, 64);
        ls += __shfl_down(ls, off, 64);
    }
    int lane = tid & 63, wid = tid >> 6;
    if (lane == 0) { redH[wid] = term; redL[wid] = ls; }
    __syncthreads();
    if (tid == 0) {
        float H = 0.f, L = 0.f;
#pragma unroll
        for (int i = 0; i < 16; ++i) { H += redH[i]; L += redL[i]; }
        out[(size_t)NROWS * D + 0] = 2.0f * (L / (float)(NROWS * D));
        out[(size_t)NROWS * D + 1] = expf(-H);
    }
}

extern "C" void kernel_launch(void* const* d_in, const int* in_sizes, int n_in,
                              void* d_out, int out_size, void* d_ws, size_t ws_size,
                              hipStream_t stream) {
    const float* X = (const float*)d_in[0];   // [64,2048,64] fp32
    const float* E = (const float*)d_in[1];   // [64,1024]   fp32
    float* out = (float*)d_out;

    char* w = (char*)d_ws;
    unsigned short* ehT = (unsigned short*)(w + 0);
    float* eTf          = (float*)(w + 131072);
    float* e2p          = (float*)(w + 393216);
    int* hist           = (int*)(w + 409600);
    float* wavesum      = (float*)(w + 413696);

    prep_kernel<<<16, 256, 0, stream>>>(E, ehT, eTf, e2p, hist);
    score_kernel<<<NROWS / 128, 256, 0, stream>>>(X, ehT, e2p, eTf, hist, wavesum, out);
    finalize_kernel<<<1, 1024, 0, stream>>>(hist, wavesum, out);
}